// Round 4
// baseline (591.598 us; speedup 1.0000x reference)
//
#include <hip/hip_runtime.h>

#define B_SZ 256
#define S_LEN 512
#define NT 128
#define PAD 127
#define LN2F 0.69314718055994530942f
#define RENORM 0x1p-62f

typedef float v2f __attribute__((ext_vector_type(2)));
typedef float v4f __attribute__((ext_vector_type(4)));

// Barrier draining only LDS (lgkmcnt), NOT vmcnt — emission prefetch loads
// stay in flight across steps.
__device__ __forceinline__ void lds_barrier() {
    asm volatile("s_waitcnt lgkmcnt(0)\n\ts_barrier" ::: "memory");
}

// One block per batch; TWO waves (128 threads); lane owns ONE state j=64w+l.
// Every lane needs all 128 alpha values -> LDS read address is fully
// wave-uniform (pure broadcast, zero bank conflicts). col = exp(trans[:,j])
// lives in 128 VGPRs/lane. Inner loop is plain-C v2f math so LLVM emits
// v_pk_fma_f32 with subregister operands (no asm-constraint mov copies).
// No readlane, no shfl merge, no cross-wave reduce; one 2-wave barrier/step.
__global__ __launch_bounds__(128, 1) void crf_fused(
    const float* __restrict__ em,      // (B,S,T)
    const int*   __restrict__ tags,    // (B,S)
    const float* __restrict__ startT,  // (T)
    const float* __restrict__ endT,    // (T)
    const float* __restrict__ trans,   // (T,T)
    float* __restrict__ out)
{
    const int b   = blockIdx.x;
    const int tid = threadIdx.x;
    const int w   = tid >> 6;          // wave 0..1
    const int l   = tid & 63;          // lane
    const int j   = tid;               // this lane's output state (0..127)

    __shared__ __align__(16) float alphaL[2][NT];  // parity alpha buffers
    __shared__ float maskv[S_LEN + 1]; // per-step mask as float (padded)
    __shared__ float nred[2];
    __shared__ int   cred[2];

    const float* em_b = em + (size_t)b * S_LEN * NT;
    const int*   tg_b = tags + (size_t)b * S_LEN;
    const float* emj  = em_b + j;      // per-lane emission column

    // ---- stage per-step masks ----
    for (int q = tid; q < S_LEN; q += 128)
        maskv[q] = (tg_b[q] != PAD) ? 1.0f : 0.0f;
    if (tid == 0) maskv[S_LEN] = 1.0f;

    // ---- numerator partial + valid count (wave w covers chunks 4w..4w+3) ----
    float numSum = 0.f;
    int   cnt    = 0;
    #pragma unroll
    for (int q = 0; q < 4; ++q) {
        int t  = 64 * (4 * w + q) + l;
        int tv = tg_b[t];
        cnt += (tv != PAD) ? 1 : 0;
        float emg = em_b[(size_t)t * NT + tv];
        if (t == 0) {
            numSum += startT[tv] + emg;
        } else {
            int tp = tg_b[t - 1];
            float v = trans[tp * NT + tv] + emg;
            numSum += (tv != PAD) ? v : 0.f;
        }
    }
    #pragma unroll
    for (int off = 32; off > 0; off >>= 1) {
        numSum += __shfl_down(numSum, off, 64);
        cnt    += __shfl_down(cnt, off, 64);
    }
    if (l == 0) { nred[w] = numSum; cred[w] = cnt; }

    // ---- column registers: colp[m] = {expT[2m][j], expT[2m+1][j]} ----
    v2f colp[64];
    #pragma unroll
    for (int m = 0; m < 64; ++m) {
        colp[m].x = __expf(trans[(2 * m)     * NT + j]);
        colp[m].y = __expf(trans[(2 * m + 1) * NT + j]);
    }

    // ---- alpha init (t=0): each lane writes its own state ----
    float aOld = __expf(startT[j] + em_b[j]);
    alphaL[0][j] = aOld;

    // ---- named-register emission pipeline: slot s holds em[t=s+1 (mod 8)][j] ----
    float rE0 = emj[1 * NT], rE1 = emj[2 * NT], rE2 = emj[3 * NT], rE3 = emj[4 * NT];
    float rE4 = emj[5 * NT], rE5 = emj[6 * NT], rE6 = emj[7 * NT], rE7 = emj[8 * NT];

    __syncthreads();   // maskv + nred + alphaL[0] visible; one-time full barrier

    float mvCur = maskv[1];            // mask for the first step (prefetched)

#define STEP(SL, T, RN)                                                      \
  {                                                                          \
    const int t_ = (T);                                                      \
    const v4f* qb_ = (const v4f*)&alphaL[(t_ + 1) & 1][0];  /* uniform */    \
    float mv_ = mvCur;                                                       \
    mvCur = maskv[t_ + 1];             /* prefetch next step's mask */       \
    int   tn_ = (t_ + 8 < S_LEN) ? t_ + 8 : S_LEN - 1;                       \
    float nE_ = emj[(size_t)tn_ * NT];                                       \
    float e_  = __expf(rE##SL);                                              \
    rE##SL = nE_;                                                            \
    v2f ac0_ = {0.f,0.f}, ac1_ = {0.f,0.f}, ac2_ = {0.f,0.f}, ac3_ = {0.f,0.f};\
    _Pragma("unroll")                                                        \
    for (int i_ = 0; i_ < 32; i_ += 2) {                                     \
      v4f q0_ = qb_[i_], q1_ = qb_[i_ + 1];                                  \
      ac0_ += (v2f){q0_.x, q0_.y} * colp[2 * i_];                            \
      ac1_ += (v2f){q0_.z, q0_.w} * colp[2 * i_ + 1];                        \
      ac2_ += (v2f){q1_.x, q1_.y} * colp[2 * i_ + 2];                        \
      ac3_ += (v2f){q1_.z, q1_.w} * colp[2 * i_ + 3];                        \
    }                                                                        \
    v2f p_ = (ac0_ + ac1_) + (ac2_ + ac3_);                                  \
    float h_  = p_.x + p_.y;           /* full 128-k dot for state j */      \
    float nw_ = h_ * e_;               /* fold exp(em) */                    \
    float sel_ = (mv_ != 0.0f) ? nw_ : aOld;                                 \
    if (RN) sel_ *= RENORM;                                                  \
    aOld = sel_;                                                             \
    alphaL[t_ & 1][j] = sel_;          /* 2-way bank alias: free */          \
    lds_barrier();                                                           \
  }

    // chunk 0: t = 1..7  (slot = (t-1)&7)
    STEP(0, 1, false) STEP(1, 2, false) STEP(2, 3, false) STEP(3, 4, false)
    STEP(4, 5, false) STEP(5, 6, false) STEP(6, 7, false)

    // chunks 1..63: t = 8c .. 8c+7 ; renorm at t = 8c (63 renorms total)
    for (int c = 1; c < 64; ++c) {
        const int t0 = c * 8;
        STEP(7, t0,     true)
        STEP(0, t0 + 1, false) STEP(1, t0 + 2, false) STEP(2, t0 + 3, false)
        STEP(3, t0 + 4, false) STEP(4, t0 + 5, false) STEP(5, t0 + 6, false)
        STEP(6, t0 + 7, false)
    }
#undef STEP

    // ---- finalize: wave 0 computes denominator and writes output ----
    // alpha_511 lives in alphaL[511 & 1] = alphaL[1]; last STEP's barrier
    // makes it visible.
    if (w == 0) {
        float ax = alphaL[1][l];
        float ay = alphaL[1][64 + l];
        float pe = ax * __expf(endT[l]) + ay * __expf(endT[64 + l]);
        #pragma unroll
        for (int off = 32; off > 0; off >>= 1)
            pe += __shfl_down(pe, off, 64);
        if (l == 0) {
            int   cT   = cred[0] + cred[1];
            int   last = tg_b[cT - 1];
            float num  = nred[0] + nred[1] + endT[last];
            float den  = 63.0f * 62.0f * LN2F + logf(pe);
            atomicAdd(out, (num - den) * (1.0f / (float)B_SZ));
        }
    }
}

extern "C" void kernel_launch(void* const* d_in, const int* in_sizes, int n_in,
                              void* d_out, int out_size, void* d_ws, size_t ws_size,
                              hipStream_t stream) {
    const float* em     = (const float*)d_in[0];
    const int*   tags   = (const int*)d_in[1];
    const float* startT = (const float*)d_in[2];
    const float* endT   = (const float*)d_in[3];
    const float* trans  = (const float*)d_in[4];
    float* out = (float*)d_out;

    hipMemsetAsync(out, 0, sizeof(float), stream);
    crf_fused<<<B_SZ, 128, 0, stream>>>(em, tags, startT, endT, trans, out);
}

// Round 5
// 367.481 us; speedup vs baseline: 1.6099x; 1.6099x over previous
//
#include <hip/hip_runtime.h>

#define B_SZ 256
#define S_LEN 512
#define NT 128
#define PAD 127
#define LN2F 0.69314718055994530942f
#define RENORM 0x1p-62f

typedef float v2f __attribute__((ext_vector_type(2)));

__device__ __forceinline__ float bcastf(float v, int k) {
    return __uint_as_float((unsigned)__builtin_amdgcn_readlane((int)__float_as_uint(v), k));
}

// Barrier draining only LDS (lgkmcnt), NOT vmcnt — emission prefetch loads
// stay in flight across steps.
__device__ __forceinline__ void lds_barrier() {
    asm volatile("s_waitcnt lgkmcnt(0)\n\ts_barrier" ::: "memory");
}

// TWO independent batch-chains per block (512 thr): waves 0-3 = batch 2*blk,
// waves 4-7 = batch 2*blk+1. Chains share the CU so one chain's post-barrier
// LDS-latency stall is filled by the other chain's FMA issue (r0 measured
// ~405 stall cyc/step; LDS broadcast reads are NOT a viable alternative —
// r3/r4 showed uniform-address ds_read pays full per-lane return cost).
// Within a chain: K-split, alpha as SCALAR ax/ay, broadcast via readlane
// feeding v_fmac with SGPR operand: 3 VALU/k (readlane+2 fmac), no splat
// movs, no inline-asm operand constraints (r2/r3 tax), no LDS broadcast.
__global__ __launch_bounds__(512, 2) void crf_fused(
    const float* __restrict__ em,      // (B,S,T)
    const int*   __restrict__ tags,    // (B,S)
    const float* __restrict__ startT,  // (T)
    const float* __restrict__ endT,    // (T)
    const float* __restrict__ trans,   // (T,T)
    float* __restrict__ out)
{
    const int tid = threadIdx.x;
    const int g   = tid >> 8;          // chain 0/1
    const int ct  = tid & 255;         // thread within chain
    const int cw  = ct >> 6;           // wave within chain 0..3
    const int l   = tid & 63;          // lane
    const int b   = blockIdx.x * 2 + g;

    __shared__ __align__(16) v2f bufp[2][2][4][64]; // [chain][parity][wave][lane]
    __shared__ float maskv[2][S_LEN];  // per-chain per-step mask
    __shared__ float nred[2][4];
    __shared__ int   cred[2][4];

    const float* em_b = em + (size_t)b * S_LEN * NT;
    const int*   tg_b = tags + (size_t)b * S_LEN;

    // ---- stage per-step masks (per chain) ----
    for (int q = ct; q < S_LEN; q += 256)
        maskv[g][q] = (tg_b[q] != PAD) ? 1.0f : 0.0f;

    // ---- numerator partial + valid count (wave cw covers chunks 2cw,2cw+1) ----
    float numSum = 0.f;
    int   cnt    = 0;
    #pragma unroll
    for (int q = 0; q < 2; ++q) {
        int t  = 64 * (2 * cw + q) + l;
        int tv = tg_b[t];
        cnt += (tv != PAD) ? 1 : 0;
        float emg = em_b[(size_t)t * NT + tv];
        if (t == 0) {
            numSum += startT[tv] + emg;
        } else {
            int tp = tg_b[t - 1];
            float v = trans[tp * NT + tv] + emg;
            numSum += (tv != PAD) ? v : 0.f;
        }
    }
    #pragma unroll
    for (int off = 32; off > 0; off >>= 1) {
        numSum += __shfl_down(numSum, off, 64);
        cnt    += __shfl_down(cnt, off, 64);
    }
    if (l == 0) { nred[g][cw] = numSum; cred[g][cw] = cnt; }

    // ---- column registers for this wave's K-slice: k in [32cw, 32cw+32) ----
    const int k0 = 32 * cw;
    float colx[32], coly[32];
    #pragma unroll
    for (int i = 0; i < 32; ++i) {
        colx[i] = __expf(trans[(k0 + i) * NT + l]);
        coly[i] = __expf(trans[(k0 + i) * NT + 64 + l]);
    }

    // ---- alpha init (t=0), replicated on all 4 waves of the chain ----
    float ax = __expf(startT[l]      + em_b[l]);
    float ay = __expf(startT[64 + l] + em_b[64 + l]);

    const bool useX = (cw < 2);
    const int  base = (cw & 1) * 32;

    // ---- named-register emission pipeline: slot s holds em for t = s+1 (mod 8) ----
    float rA0 = em_b[1 * NT + l], rB0 = em_b[1 * NT + 64 + l];
    float rA1 = em_b[2 * NT + l], rB1 = em_b[2 * NT + 64 + l];
    float rA2 = em_b[3 * NT + l], rB2 = em_b[3 * NT + 64 + l];
    float rA3 = em_b[4 * NT + l], rB3 = em_b[4 * NT + 64 + l];
    float rA4 = em_b[5 * NT + l], rB4 = em_b[5 * NT + 64 + l];
    float rA5 = em_b[6 * NT + l], rB5 = em_b[6 * NT + 64 + l];
    float rA6 = em_b[7 * NT + l], rB6 = em_b[7 * NT + 64 + l];
    float rA7 = em_b[8 * NT + l], rB7 = em_b[8 * NT + 64 + l];

    __syncthreads();   // maskv + nred visible; one-time full barrier

#define STEP(SL, T, RN)                                                      \
  {                                                                          \
    const int t_   = (T);                                                    \
    const int par_ = t_ & 1;                                                 \
    int   tn_ = (t_ + 8 < S_LEN) ? t_ + 8 : S_LEN - 1;                       \
    float nA_ = em_b[(size_t)tn_ * NT + l];                                  \
    float nB_ = em_b[(size_t)tn_ * NT + 64 + l];                             \
    float mv_ = maskv[g][t_];                                                \
    float e0_ = __expf(rA##SL);                                              \
    float e1_ = __expf(rB##SL);                                              \
    rA##SL = nA_; rB##SL = nB_;                                              \
    float sreg_ = useX ? ax : ay;                                            \
    float px0_=0.f, px1_=0.f, px2_=0.f, px3_=0.f;                            \
    float py0_=0.f, py1_=0.f, py2_=0.f, py3_=0.f;                            \
    _Pragma("unroll")                                                        \
    for (int i_ = 0; i_ < 32; i_ += 4) {                                     \
      float s0_ = bcastf(sreg_, base + i_);                                  \
      float s1_ = bcastf(sreg_, base + i_ + 1);                              \
      float s2_ = bcastf(sreg_, base + i_ + 2);                              \
      float s3_ = bcastf(sreg_, base + i_ + 3);                              \
      px0_ += s0_ * colx[i_];     py0_ += s0_ * coly[i_];                    \
      px1_ += s1_ * colx[i_ + 1]; py1_ += s1_ * coly[i_ + 1];                \
      px2_ += s2_ * colx[i_ + 2]; py2_ += s2_ * coly[i_ + 2];                \
      px3_ += s3_ * colx[i_ + 3]; py3_ += s3_ * coly[i_ + 3];                \
    }                                                                        \
    float px_ = (px0_ + px1_) + (px2_ + px3_);                               \
    float py_ = (py0_ + py1_) + (py2_ + py3_);                               \
    px_ *= e0_;  py_ *= e1_;            /* fold exp(em) into partial */      \
    bufp[g][par_][cw][l] = (v2f){px_, py_};   /* one ds_write_b64 */         \
    lds_barrier();                                                           \
    v2f q0_ = bufp[g][par_][0][l], q1_ = bufp[g][par_][1][l];                \
    v2f q2_ = bufp[g][par_][2][l], q3_ = bufp[g][par_][3][l];                \
    v2f qs_ = (q0_ + q1_) + (q2_ + q3_);                                     \
    bool u_  = (mv_ != 0.0f);                                                \
    ax = u_ ? qs_.x : ax;                                                    \
    ay = u_ ? qs_.y : ay;                                                    \
    if (RN) { ax *= RENORM; ay *= RENORM; }                                  \
  }

    // chunk 0: t = 1..7  (slot = (t-1)&7)
    STEP(0, 1, false) STEP(1, 2, false) STEP(2, 3, false) STEP(3, 4, false)
    STEP(4, 5, false) STEP(5, 6, false) STEP(6, 7, false)

    // chunks 1..63: t = 8c .. 8c+7 ; renorm at t = 8c (63 renorms total)
    for (int c = 1; c < 64; ++c) {
        const int t0 = c * 8;
        STEP(7, t0,     true)
        STEP(0, t0 + 1, false) STEP(1, t0 + 2, false) STEP(2, t0 + 3, false)
        STEP(3, t0 + 4, false) STEP(4, t0 + 5, false) STEP(5, t0 + 6, false)
        STEP(6, t0 + 7, false)
    }
#undef STEP

    // ---- finalize: wave 0 of each chain computes its denominator ----
    if (cw == 0) {
        float pe = ax * __expf(endT[l]) + ay * __expf(endT[64 + l]);
        #pragma unroll
        for (int off = 32; off > 0; off >>= 1)
            pe += __shfl_down(pe, off, 64);
        if (l == 0) {
            int   cT   = (cred[g][0] + cred[g][1]) + (cred[g][2] + cred[g][3]);
            int   last = tg_b[cT - 1];
            float num  = (nred[g][0] + nred[g][1]) + (nred[g][2] + nred[g][3])
                         + endT[last];
            float den  = 63.0f * 62.0f * LN2F + logf(pe);
            atomicAdd(out, (num - den) * (1.0f / (float)B_SZ));
        }
    }
}

extern "C" void kernel_launch(void* const* d_in, const int* in_sizes, int n_in,
                              void* d_out, int out_size, void* d_ws, size_t ws_size,
                              hipStream_t stream) {
    const float* em     = (const float*)d_in[0];
    const int*   tags   = (const int*)d_in[1];
    const float* startT = (const float*)d_in[2];
    const float* endT   = (const float*)d_in[3];
    const float* trans  = (const float*)d_in[4];
    float* out = (float*)d_out;

    hipMemsetAsync(out, 0, sizeof(float), stream);
    crf_fused<<<B_SZ / 2, 512, 0, stream>>>(em, tags, startT, endT, trans, out);
}